// Round 7
// baseline (331.337 us; speedup 1.0000x reference)
//
#include <hip/hip_runtime.h>

typedef float v2f __attribute__((ext_vector_type(2)));
typedef float v4f __attribute__((ext_vector_type(4)));

#define BB 32
#define LL 32768
#define HH 32
#define NN2 8
#define NCOND 4
#define NCHUNK 256
#define LC (LL / NCHUNK)   // 128
#define CPB 2              // chunks per block (pass_a / pass_c)
#define TILEF (CPB * LC * HH)   // 8192 floats = 32 KB LDS tile

// ws layout (floats):
//  PARAM_OFF: per h: [wr x8][wi x8][ctr x8][cti x8]   H*32  = 1024
//  WLC_OFF  : per (h,n): (wLc_r, wLc_i)               H*N2*2 = 512   (at 1024)
//  FILM_OFF : per (b,h): (gamma, beta)                B*H*2  = 2048  (at 1536)
//  S_OFF    : per (b,c,h): [zr x8][zi x8]             B*H*NCHUNK*16  (at 4096)
#define PARAM_OFF 0
#define WLC_OFF   1024
#define FILM_OFF  1536
#define S_OFF     4096

static __device__ __forceinline__ v2f vfma(v2f a, v2f b, v2f c) {
  return __builtin_elementwise_fma(a, b, c);
}

// Packed fp32 math, forced (VOP3P). If the compiler was already packing,
// these are neutral; if it was emitting 2x v_fma_f32, these halve the
// recurrence VALU count.
static __device__ __forceinline__ v2f pk_fma(v2f a, v2f b, v2f c) {
  v2f d;
  asm("v_pk_fma_f32 %0, %1, %2, %3" : "=v"(d) : "v"(a), "v"(b), "v"(c));
  return d;
}
static __device__ __forceinline__ v2f pk_mul(v2f a, v2f b) {
  v2f d;
  asm("v_pk_mul_f32 %0, %1, %2" : "=v"(d) : "v"(a), "v"(b));
  return d;
}

__global__ void setup_kernel(const float* __restrict__ log_dt,
                             const float* __restrict__ C_re,
                             const float* __restrict__ C_im,
                             const float* __restrict__ log_A_real,
                             const float* __restrict__ A_imag,
                             const float* __restrict__ cond,
                             const float* __restrict__ film_W,
                             const float* __restrict__ film_b,
                             float* __restrict__ ws) {
  int idx = blockIdx.x * blockDim.x + threadIdx.x;
  if (idx < HH * NN2) {
    int h = idx >> 3, n = idx & (NN2 - 1);
    float dt = expf(log_dt[h]);
    float ar = -expf(log_A_real[idx]);
    float ai = A_imag[idx];
    float dr = ar * dt, di = ai * dt;        // dtA
    float er = expf(dr);
    float wr = er * cosf(di);
    float wi = er * sinf(di);
    // (exp(dtA)-1)/A
    float den = ar * ar + ai * ai;
    float tr = ((wr - 1.f) * ar + wi * ai) / den;
    float ti = (wi * ar - (wr - 1.f) * ai) / den;
    float cr = C_re[idx], ci = C_im[idx];
    float ctr = 2.f * (cr * tr - ci * ti);
    float cti = 2.f * (cr * ti + ci * tr);
    float* p = ws + PARAM_OFF + h * 32;
    p[n] = wr; p[n + 8] = wi; p[n + 16] = ctr; p[n + 24] = cti;
    // w^LC
    float eL  = expf(dr * (float)LC);
    float wlr = eL * cosf(di * (float)LC);
    float wli = eL * sinf(di * (float)LC);
    float* q = ws + WLC_OFF + idx * 2;
    q[0] = wlr; q[1] = wli;
  }
  int f = idx - HH * NN2;
  if (f >= 0 && f < BB * HH) {
    int b = f >> 5, h = f & (HH - 1);
    float g  = film_b[h];
    float be = film_b[h + HH];
    #pragma unroll
    for (int c2 = 0; c2 < NCOND; c2++) {
      float cv = cond[b * NCOND + c2];
      g  = fmaf(cv, film_W[c2 * 2 * HH + h], g);
      be = fmaf(cv, film_W[c2 * 2 * HH + HH + h], be);
    }
    float* p = ws + FILM_OFF + f * 2;
    p[0] = g; p[1] = be;
  }
}

// pass_a: block (128 thr) owns a contiguous 32 KB region of x (2 chunks).
// Stage via float4, scan out of LDS. tid = h(5b) | nh(1b) | cl(1b).
__global__ __launch_bounds__(128) void pass_a(const float* __restrict__ x,
                                              float* __restrict__ ws) {
  __shared__ float xs[TILEF];   // 32 KB
  const int tid = threadIdx.x;
  const int h  = tid & (HH - 1);
  const int nh = (tid >> 5) & 1;
  const int cl = tid >> 6;                 // 0..1 local chunk
  const int b  = blockIdx.x >> 7;          // 128 block-groups per b
  const int cg = blockIdx.x & 127;
  const int c  = cg * CPB + cl;            // global chunk

  const v4f* xg = (const v4f*)(x + ((size_t)b * LL + (size_t)cg * CPB * LC) * HH);
  v4f* ls = (v4f*)xs;
  #pragma unroll
  for (int it = 0; it < TILEF / 4 / 128; it++) {
    int idx = it * 128 + tid;
    ls[idx] = xg[idx];
  }

  const v2f* pp = (const v2f*)(ws + PARAM_OFF + h * 32);
  v2f wr[2], wi[2], nwi[2], zr[2], zi[2];
  #pragma unroll
  for (int g = 0; g < 2; g++) {
    wr[g] = pp[nh * 2 + g]; wi[g] = pp[4 + nh * 2 + g];
    nwi[g] = (v2f){-wi[g].x, -wi[g].y};
    zr[g] = (v2f){0.f, 0.f}; zi[g] = (v2f){0.f, 0.f};
  }
  __syncthreads();

  const float* xt = xs + (cl * LC) * HH + h;
  #pragma unroll 8
  for (int i = 0; i < LC; i++) {
    float u = xt[i * HH];
    v2f us = (v2f){u, u};
    #pragma unroll
    for (int g = 0; g < 2; g++) {
      v2f t0  = pk_fma(nwi[g], zi[g], us);
      v2f nzr = pk_fma(wr[g], zr[g], t0);
      v2f t1  = pk_mul(wi[g], zr[g]);
      zi[g]   = pk_fma(wr[g], zi[g], t1);
      zr[g]   = nzr;
    }
  }
  const size_t flatbch = ((size_t)b * NCHUNK + c) * HH + h;
  v2f* Sp = (v2f*)(ws + S_OFF + flatbch * 16);
  #pragma unroll
  for (int g = 0; g < 2; g++) {
    Sp[nh * 2 + g]     = zr[g];
    Sp[4 + nh * 2 + g] = zi[g];
  }
}

// Block-parallel chunk-prefix scan (Hillis-Steele, 8 steps). Unchanged.
__global__ __launch_bounds__(256) void pass_b(float* __restrict__ ws) {
  const int bh = blockIdx.x;            // 0 .. B*H-1
  const int b  = bh >> 5;
  const int h  = bh & (HH - 1);
  const int t  = threadIdx.x;           // chunk index

  __shared__ __align__(16) float Lbuf[NCHUNK][18];   // 16 payload + 2 pad

  float* Sp = ws + S_OFF +
              ((size_t)b * (NCHUNK * HH) + (size_t)t * HH + h) * 16;

  v2f zr[4], zi[4];
  #pragma unroll
  for (int g = 0; g < 4; g++) {
    zr[g] = ((const v2f*)Sp)[g];
    zi[g] = ((const v2f*)Sp)[4 + g];
  }

  const float* q = ws + WLC_OFF + h * NN2 * 2;
  v2f mr[4], mi[4];
  #pragma unroll
  for (int g = 0; g < 4; g++) {
    mr[g] = (v2f){q[4 * g + 0], q[4 * g + 2]};
    mi[g] = (v2f){q[4 * g + 1], q[4 * g + 3]};
  }

  v2f* rowv = (v2f*)&Lbuf[t][0];
  #pragma unroll
  for (int g = 0; g < 4; g++) { rowv[g] = zr[g]; rowv[4 + g] = zi[g]; }
  __syncthreads();

  #pragma unroll
  for (int d = 1; d < NCHUNK; d <<= 1) {
    v2f ar[4], ai[4];
    #pragma unroll
    for (int g = 0; g < 4; g++) { ar[g] = (v2f){0.f, 0.f}; ai[g] = (v2f){0.f, 0.f}; }
    if (t >= d) {
      const v2f* prow = (const v2f*)&Lbuf[t - d][0];
      #pragma unroll
      for (int g = 0; g < 4; g++) { ar[g] = prow[g]; ai[g] = prow[4 + g]; }
    }
    __syncthreads();
    #pragma unroll
    for (int g = 0; g < 4; g++) {
      zr[g] = vfma(mr[g], ar[g], vfma(-mi[g], ai[g], zr[g]));
      zi[g] = vfma(mr[g], ai[g], vfma(mi[g], ar[g], zi[g]));
      rowv[g] = zr[g]; rowv[4 + g] = zi[g];
      v2f nmr = vfma(mr[g], mr[g], -(mi[g] * mi[g]));
      v2f nmi = (mr[g] + mr[g]) * mi[g];
      mr[g] = nmr; mi[g] = nmi;
    }
    __syncthreads();
  }

  v2f er[4], ei[4];
  #pragma unroll
  for (int g = 0; g < 4; g++) { er[g] = (v2f){0.f, 0.f}; ei[g] = (v2f){0.f, 0.f}; }
  if (t > 0) {
    const v2f* prow = (const v2f*)&Lbuf[t - 1][0];
    #pragma unroll
    for (int g = 0; g < 4; g++) { er[g] = prow[g]; ei[g] = prow[4 + g]; }
  }
  #pragma unroll
  for (int g = 0; g < 4; g++) {
    ((v2f*)Sp)[g] = er[g];
    ((v2f*)Sp)[4 + g] = ei[g];
  }
}

// pass_c: same 32 KB staging; packed-asm recurrence; cheap sigmoid-gelu.
__global__ __launch_bounds__(128) void pass_c(const float* __restrict__ x,
                                              const float* __restrict__ Dv,
                                              float* __restrict__ out,
                                              float* __restrict__ ws) {
  __shared__ float xs[TILEF];   // 32 KB
  const int tid = threadIdx.x;
  const int h  = tid & (HH - 1);
  const int nh = (tid >> 5) & 1;
  const int cl = tid >> 6;
  const int b  = blockIdx.x >> 7;
  const int cg = blockIdx.x & 127;
  const int c  = cg * CPB + cl;

  const v4f* xg = (const v4f*)(x + ((size_t)b * LL + (size_t)cg * CPB * LC) * HH);
  v4f* ls = (v4f*)xs;
  #pragma unroll
  for (int it = 0; it < TILEF / 4 / 128; it++) {
    int idx = it * 128 + tid;
    ls[idx] = xg[idx];
  }

  const v2f* pp = (const v2f*)(ws + PARAM_OFF + h * 32);
  v2f wr[2], wi[2], nwi[2], ctr[2], ncti[2], zr[2], zi[2];
  #pragma unroll
  for (int g = 0; g < 2; g++) {
    wr[g]  = pp[nh * 2 + g];      wi[g]  = pp[4 + nh * 2 + g];
    nwi[g] = (v2f){-wi[g].x, -wi[g].y};
    ctr[g] = pp[8 + nh * 2 + g];
    v2f ct = pp[12 + nh * 2 + g];
    ncti[g] = (v2f){-ct.x, -ct.y};
  }
  const size_t flatbch = ((size_t)b * NCHUNK + c) * HH + h;
  const v2f* Zp = (const v2f*)(ws + S_OFF + flatbch * 16);
  #pragma unroll
  for (int g = 0; g < 2; g++) {
    zr[g] = Zp[nh * 2 + g];
    zi[g] = Zp[4 + nh * 2 + g];
  }
  float gamma = ws[FILM_OFF + ((size_t)b * HH + h) * 2];
  float beta  = ws[FILM_OFF + ((size_t)b * HH + h) * 2 + 1];
  float dcoef = Dv[h];
  __syncthreads();

  const float* xt = xs + (cl * LC) * HH + h;
  float* op = out + ((size_t)b * LL + (size_t)c * LC) * HH + h;
  #pragma unroll 4
  for (int i = 0; i < LC; i += 2) {
    float u0 = xt[i * HH];
    float u1 = xt[(i + 1) * HH];
    // element i
    v2f us0 = (v2f){u0, u0};
    v2f acc0 = (v2f){0.f, 0.f};
    #pragma unroll
    for (int g = 0; g < 2; g++) {
      v2f t0  = pk_fma(nwi[g], zi[g], us0);
      v2f nzr = pk_fma(wr[g], zr[g], t0);
      v2f t1  = pk_mul(wi[g], zr[g]);
      zi[g]   = pk_fma(wr[g], zi[g], t1);
      zr[g]   = nzr;
      acc0 = pk_fma(ctr[g], zr[g], acc0);
      acc0 = pk_fma(ncti[g], zi[g], acc0);
    }
    // element i+1
    v2f us1 = (v2f){u1, u1};
    v2f acc1 = (v2f){0.f, 0.f};
    #pragma unroll
    for (int g = 0; g < 2; g++) {
      v2f t0  = pk_fma(nwi[g], zi[g], us1);
      v2f nzr = pk_fma(wr[g], zr[g], t0);
      v2f t1  = pk_mul(wi[g], zr[g]);
      zi[g]   = pk_fma(wr[g], zi[g], t1);
      zr[g]   = nzr;
      acc1 = pk_fma(ctr[g], zr[g], acc1);
      acc1 = pk_fma(ncti[g], zi[g], acc1);
    }
    // combine the two n-halves (lanes l <-> l+32 hold the other 4 modes)
    float y0 = acc0.x + acc0.y;
    float y1 = acc1.x + acc1.y;
    y0 += __shfl_xor(y0, 32, 64);
    y1 += __shfl_xor(y1, 32, 64);
    // all 64 lanes finish one element each: nh=0 -> i, nh=1 -> i+1
    float ysel = nh ? y1 : y0;
    float usel = nh ? u1 : u0;
    float y = fmaf(dcoef, usel, ysel);
    y = fmaf(gamma, y, beta);
    // gelu(tanh approx) == y * sigmoid(1.5957691*y + 0.0713548755*y^3)
    float y2 = y * y;
    float s  = y * fmaf(0.0713548755f, y2, 1.5957691216f);
    float ex = __expf(-s);
    float r  = __fdividef(1.f, 1.f + ex);
    __builtin_nontemporal_store(y * r, op + (size_t)(i + nh) * HH);
  }
}

extern "C" void kernel_launch(void* const* d_in, const int* in_sizes, int n_in,
                              void* d_out, int out_size, void* d_ws, size_t ws_size,
                              hipStream_t stream) {
  const float* x          = (const float*)d_in[0];
  const float* cond       = (const float*)d_in[1];
  const float* log_dt     = (const float*)d_in[2];
  const float* C_re       = (const float*)d_in[3];
  const float* C_im       = (const float*)d_in[4];
  const float* log_A_real = (const float*)d_in[5];
  const float* A_imag     = (const float*)d_in[6];
  const float* Dv         = (const float*)d_in[7];
  const float* film_W     = (const float*)d_in[8];
  const float* film_b     = (const float*)d_in[9];
  float* out = (float*)d_out;
  float* ws  = (float*)d_ws;

  setup_kernel<<<5, 256, 0, stream>>>(log_dt, C_re, C_im, log_A_real, A_imag,
                                      cond, film_W, film_b, ws);
  pass_a<<<BB * (NCHUNK / CPB), 128, 0, stream>>>(x, ws);
  pass_b<<<BB * HH, 256, 0, stream>>>(ws);
  pass_c<<<BB * (NCHUNK / CPB), 128, 0, stream>>>(x, Dv, out, ws);
}

// Round 8
// 307.551 us; speedup vs baseline: 1.0773x; 1.0773x over previous
//
#include <hip/hip_runtime.h>

typedef float v2f __attribute__((ext_vector_type(2)));

#define BB 32
#define LL 32768
#define HH 32
#define NN2 8
#define NCOND 4
#define NCHUNK 256
#define LC (LL / NCHUNK)   // 128

// ws layout (floats):
//  PARAM_OFF: per h: [wr x8][wi x8][ctr x8][cti x8]   H*32  = 1024
//  WLC_OFF  : per (h,n): (wLc_r, wLc_i)               H*N2*2 = 512   (at 1024)
//  FILM_OFF : per (b,h): (gamma, beta)                B*H*2  = 2048  (at 1536)
//  S_OFF    : per (b,c,h): [zr x8][zi x8]             B*H*NCHUNK*16  (at 4096)
#define PARAM_OFF 0
#define WLC_OFF   1024
#define FILM_OFF  1536
#define S_OFF     4096

static __device__ __forceinline__ v2f vfma(v2f a, v2f b, v2f c) {
  return __builtin_elementwise_fma(a, b, c);
}

// Forced packed fp32 (VOP3P). The compiler scalarizes v2f builtins to
// 2x v_fma_f32; these keep the recurrence at 1 instr per 2 modes.
static __device__ __forceinline__ v2f pk_fma(v2f a, v2f b, v2f c) {
  v2f d;
  asm("v_pk_fma_f32 %0, %1, %2, %3" : "=v"(d) : "v"(a), "v"(b), "v"(c));
  return d;
}
static __device__ __forceinline__ v2f pk_mul(v2f a, v2f b) {
  v2f d;
  asm("v_pk_mul_f32 %0, %1, %2" : "=v"(d) : "v"(a), "v"(b));
  return d;
}

__global__ void setup_kernel(const float* __restrict__ log_dt,
                             const float* __restrict__ C_re,
                             const float* __restrict__ C_im,
                             const float* __restrict__ log_A_real,
                             const float* __restrict__ A_imag,
                             const float* __restrict__ cond,
                             const float* __restrict__ film_W,
                             const float* __restrict__ film_b,
                             float* __restrict__ ws) {
  int idx = blockIdx.x * blockDim.x + threadIdx.x;
  if (idx < HH * NN2) {
    int h = idx >> 3, n = idx & (NN2 - 1);
    float dt = expf(log_dt[h]);
    float ar = -expf(log_A_real[idx]);
    float ai = A_imag[idx];
    float dr = ar * dt, di = ai * dt;        // dtA
    float er = expf(dr);
    float wr = er * cosf(di);
    float wi = er * sinf(di);
    // (exp(dtA)-1)/A
    float den = ar * ar + ai * ai;
    float tr = ((wr - 1.f) * ar + wi * ai) / den;
    float ti = (wi * ar - (wr - 1.f) * ai) / den;
    float cr = C_re[idx], ci = C_im[idx];
    float ctr = 2.f * (cr * tr - ci * ti);
    float cti = 2.f * (cr * ti + ci * tr);
    float* p = ws + PARAM_OFF + h * 32;
    p[n] = wr; p[n + 8] = wi; p[n + 16] = ctr; p[n + 24] = cti;
    // w^LC
    float eL  = expf(dr * (float)LC);
    float wlr = eL * cosf(di * (float)LC);
    float wli = eL * sinf(di * (float)LC);
    float* q = ws + WLC_OFF + idx * 2;
    q[0] = wlr; q[1] = wli;
  }
  int f = idx - HH * NN2;
  if (f >= 0 && f < BB * HH) {
    int b = f >> 5, h = f & (HH - 1);
    float g  = film_b[h];
    float be = film_b[h + HH];
    #pragma unroll
    for (int c2 = 0; c2 < NCOND; c2++) {
      float cv = cond[b * NCOND + c2];
      g  = fmaf(cv, film_W[c2 * 2 * HH + h], g);
      be = fmaf(cv, film_W[c2 * 2 * HH + HH + h], be);
    }
    float* p = ws + FILM_OFF + f * 2;
    p[0] = g; p[1] = be;
  }
}

// n-split: two threads per (b,c,h); thread nh in {0,1} owns modes
// n = nh*4 .. nh*4+3 (2 v2f groups). Lanes l and l+32 share identical x
// addresses (one 128B line serves both). Direct global loads (no LDS) so
// occupancy stays VGPR-limited (~7-8 waves/SIMD) and hides the serial
// recurrence chain. Prefetch next 8-batch while computing current.
__global__ __launch_bounds__(256) void pass_a(const float* __restrict__ x,
                                              float* __restrict__ ws) {
  const int flat = blockIdx.x * 256 + threadIdx.x;
  const int h  = flat & (HH - 1);
  const int nh = (flat >> 5) & 1;
  const int c  = (flat >> 6) & (NCHUNK - 1);
  const int b  = flat >> 14;
  const v2f* pp = (const v2f*)(ws + PARAM_OFF + h * 32);
  v2f wr[2], wi[2], nwi[2], zr[2], zi[2];
  #pragma unroll
  for (int g = 0; g < 2; g++) {
    wr[g] = pp[nh * 2 + g]; wi[g] = pp[4 + nh * 2 + g];
    nwi[g] = (v2f){-wi[g].x, -wi[g].y};
    zr[g] = (v2f){0.f, 0.f}; zi[g] = (v2f){0.f, 0.f};
  }
  const float* xp = x + ((size_t)b * LL + (size_t)c * LC) * HH + h;
  float u[8], un[8];
  #pragma unroll
  for (int j = 0; j < 8; j++) u[j] = xp[(size_t)j * HH];
  #pragma unroll 2
  for (int i = 0; i < LC; i += 8) {
    const int ip = (i + 8 < LC) ? (i + 8) : i;   // uniform, branchless
    #pragma unroll
    for (int j = 0; j < 8; j++) un[j] = xp[(size_t)(ip + j) * HH];
    #pragma unroll
    for (int j = 0; j < 8; j++) {
      v2f us = (v2f){u[j], u[j]};
      #pragma unroll
      for (int g = 0; g < 2; g++) {
        v2f t0  = pk_fma(nwi[g], zi[g], us);
        v2f nzr = pk_fma(wr[g], zr[g], t0);
        v2f t1  = pk_mul(wi[g], zr[g]);
        zi[g]   = pk_fma(wr[g], zi[g], t1);
        zr[g]   = nzr;
      }
    }
    #pragma unroll
    for (int j = 0; j < 8; j++) u[j] = un[j];
  }
  const size_t flatbch = ((size_t)b * NCHUNK + c) * HH + h;
  v2f* Sp = (v2f*)(ws + S_OFF + flatbch * 16);
  #pragma unroll
  for (int g = 0; g < 2; g++) {
    Sp[nh * 2 + g]     = zr[g];
    Sp[4 + nh * 2 + g] = zi[g];
  }
}

// Block-parallel chunk-prefix scan (Hillis-Steele, 8 steps). Unchanged.
__global__ __launch_bounds__(256) void pass_b(float* __restrict__ ws) {
  const int bh = blockIdx.x;            // 0 .. B*H-1
  const int b  = bh >> 5;
  const int h  = bh & (HH - 1);
  const int t  = threadIdx.x;           // chunk index

  __shared__ __align__(16) float Lbuf[NCHUNK][18];   // 16 payload + 2 pad

  float* Sp = ws + S_OFF +
              ((size_t)b * (NCHUNK * HH) + (size_t)t * HH + h) * 16;

  v2f zr[4], zi[4];
  #pragma unroll
  for (int g = 0; g < 4; g++) {
    zr[g] = ((const v2f*)Sp)[g];
    zi[g] = ((const v2f*)Sp)[4 + g];
  }

  const float* q = ws + WLC_OFF + h * NN2 * 2;
  v2f mr[4], mi[4];
  #pragma unroll
  for (int g = 0; g < 4; g++) {
    mr[g] = (v2f){q[4 * g + 0], q[4 * g + 2]};
    mi[g] = (v2f){q[4 * g + 1], q[4 * g + 3]};
  }

  v2f* rowv = (v2f*)&Lbuf[t][0];
  #pragma unroll
  for (int g = 0; g < 4; g++) { rowv[g] = zr[g]; rowv[4 + g] = zi[g]; }
  __syncthreads();

  #pragma unroll
  for (int d = 1; d < NCHUNK; d <<= 1) {
    v2f ar[4], ai[4];
    #pragma unroll
    for (int g = 0; g < 4; g++) { ar[g] = (v2f){0.f, 0.f}; ai[g] = (v2f){0.f, 0.f}; }
    if (t >= d) {
      const v2f* prow = (const v2f*)&Lbuf[t - d][0];
      #pragma unroll
      for (int g = 0; g < 4; g++) { ar[g] = prow[g]; ai[g] = prow[4 + g]; }
    }
    __syncthreads();
    #pragma unroll
    for (int g = 0; g < 4; g++) {
      zr[g] = vfma(mr[g], ar[g], vfma(-mi[g], ai[g], zr[g]));
      zi[g] = vfma(mr[g], ai[g], vfma(mi[g], ar[g], zi[g]));
      rowv[g] = zr[g]; rowv[4 + g] = zi[g];
      v2f nmr = vfma(mr[g], mr[g], -(mi[g] * mi[g]));
      v2f nmi = (mr[g] + mr[g]) * mi[g];
      mr[g] = nmr; mi[g] = nmi;
    }
    __syncthreads();
  }

  v2f er[4], ei[4];
  #pragma unroll
  for (int g = 0; g < 4; g++) { er[g] = (v2f){0.f, 0.f}; ei[g] = (v2f){0.f, 0.f}; }
  if (t > 0) {
    const v2f* prow = (const v2f*)&Lbuf[t - 1][0];
    #pragma unroll
    for (int g = 0; g < 4; g++) { er[g] = prow[g]; ei[g] = prow[4 + g]; }
  }
  #pragma unroll
  for (int g = 0; g < 4; g++) {
    ((v2f*)Sp)[g] = er[g];
    ((v2f*)Sp)[4 + g] = ei[g];
  }
}

// pass_c: direct loads (no LDS), packed-asm recurrence, cheap sigmoid-gelu.
__global__ __launch_bounds__(256) void pass_c(const float* __restrict__ x,
                                              const float* __restrict__ Dv,
                                              float* __restrict__ out,
                                              float* __restrict__ ws) {
  const int flat = blockIdx.x * 256 + threadIdx.x;
  const int h  = flat & (HH - 1);
  const int nh = (flat >> 5) & 1;
  const int c  = (flat >> 6) & (NCHUNK - 1);
  const int b  = flat >> 14;
  const v2f* pp = (const v2f*)(ws + PARAM_OFF + h * 32);
  v2f wr[2], wi[2], nwi[2], ctr[2], ncti[2], zr[2], zi[2];
  #pragma unroll
  for (int g = 0; g < 2; g++) {
    wr[g]  = pp[nh * 2 + g];      wi[g]  = pp[4 + nh * 2 + g];
    nwi[g] = (v2f){-wi[g].x, -wi[g].y};
    ctr[g] = pp[8 + nh * 2 + g];
    v2f ct = pp[12 + nh * 2 + g];
    ncti[g] = (v2f){-ct.x, -ct.y};
  }
  const size_t flatbch = ((size_t)b * NCHUNK + c) * HH + h;
  const v2f* Zp = (const v2f*)(ws + S_OFF + flatbch * 16);
  #pragma unroll
  for (int g = 0; g < 2; g++) {
    zr[g] = Zp[nh * 2 + g];
    zi[g] = Zp[4 + nh * 2 + g];
  }
  float gamma = ws[FILM_OFF + ((size_t)b * HH + h) * 2];
  float beta  = ws[FILM_OFF + ((size_t)b * HH + h) * 2 + 1];
  float dcoef = Dv[h];
  const size_t off = ((size_t)b * LL + (size_t)c * LC) * HH + h;
  const float* xp = x + off;
  float* op = out + off;
  float u[8], un[8];
  #pragma unroll
  for (int j = 0; j < 8; j++) u[j] = xp[(size_t)j * HH];
  #pragma unroll 2
  for (int i = 0; i < LC; i += 8) {
    const int ip = (i + 8 < LC) ? (i + 8) : i;   // uniform, branchless
    #pragma unroll
    for (int j = 0; j < 8; j++) un[j] = xp[(size_t)(ip + j) * HH];
    #pragma unroll
    for (int j = 0; j < 8; j += 2) {
      // element j
      v2f us0 = (v2f){u[j], u[j]};
      v2f acc0 = (v2f){0.f, 0.f};
      #pragma unroll
      for (int g = 0; g < 2; g++) {
        v2f t0  = pk_fma(nwi[g], zi[g], us0);
        v2f nzr = pk_fma(wr[g], zr[g], t0);
        v2f t1  = pk_mul(wi[g], zr[g]);
        zi[g]   = pk_fma(wr[g], zi[g], t1);
        zr[g]   = nzr;
        acc0 = pk_fma(ctr[g], zr[g], acc0);
        acc0 = pk_fma(ncti[g], zi[g], acc0);
      }
      // element j+1
      v2f us1 = (v2f){u[j + 1], u[j + 1]};
      v2f acc1 = (v2f){0.f, 0.f};
      #pragma unroll
      for (int g = 0; g < 2; g++) {
        v2f t0  = pk_fma(nwi[g], zi[g], us1);
        v2f nzr = pk_fma(wr[g], zr[g], t0);
        v2f t1  = pk_mul(wi[g], zr[g]);
        zi[g]   = pk_fma(wr[g], zi[g], t1);
        zr[g]   = nzr;
        acc1 = pk_fma(ctr[g], zr[g], acc1);
        acc1 = pk_fma(ncti[g], zi[g], acc1);
      }
      // combine the two n-halves (lanes l <-> l+32 hold the other 4 modes)
      float y0 = acc0.x + acc0.y;
      float y1 = acc1.x + acc1.y;
      y0 += __shfl_xor(y0, 32, 64);
      y1 += __shfl_xor(y1, 32, 64);
      // all 64 lanes finish one element each: nh=0 -> j, nh=1 -> j+1
      float ysel = nh ? y1 : y0;
      float usel = nh ? u[j + 1] : u[j];
      float y = fmaf(dcoef, usel, ysel);
      y = fmaf(gamma, y, beta);
      // gelu(tanh approx) == y * sigmoid(1.5957691*y + 0.0713548755*y^3)
      float y2 = y * y;
      float s  = y * fmaf(0.0713548755f, y2, 1.5957691216f);
      float ex = __expf(-s);
      float r  = __fdividef(1.f, 1.f + ex);
      __builtin_nontemporal_store(y * r, op + (size_t)(i + j + nh) * HH);
    }
    #pragma unroll
    for (int j = 0; j < 8; j++) u[j] = un[j];
  }
}

extern "C" void kernel_launch(void* const* d_in, const int* in_sizes, int n_in,
                              void* d_out, int out_size, void* d_ws, size_t ws_size,
                              hipStream_t stream) {
  const float* x          = (const float*)d_in[0];
  const float* cond       = (const float*)d_in[1];
  const float* log_dt     = (const float*)d_in[2];
  const float* C_re       = (const float*)d_in[3];
  const float* C_im       = (const float*)d_in[4];
  const float* log_A_real = (const float*)d_in[5];
  const float* A_imag     = (const float*)d_in[6];
  const float* Dv         = (const float*)d_in[7];
  const float* film_W     = (const float*)d_in[8];
  const float* film_b     = (const float*)d_in[9];
  float* out = (float*)d_out;
  float* ws  = (float*)d_ws;

  setup_kernel<<<5, 256, 0, stream>>>(log_dt, C_re, C_im, log_A_real, A_imag,
                                      cond, film_W, film_b, ws);
  pass_a<<<(BB * HH * NCHUNK * 2) / 256, 256, 0, stream>>>(x, ws);
  pass_b<<<BB * HH, 256, 0, stream>>>(ws);
  pass_c<<<(BB * HH * NCHUNK * 2) / 256, 256, 0, stream>>>(x, Dv, out, ws);
}